// Round 10
// baseline (119.967 us; speedup 1.0000x reference)
//
#include <hip/hip_runtime.h>
#include <hip/hip_bf16.h>
#include <math.h>

#define BB 4
#define HH 8
#define PP 32
#define NN 32
#define DD 16
#define LL 1024      // PP*NN
#define NFF 6
#define PREDL 96
#define SEQL 512
#define EPSF 1.1920928955078125e-07f
#define KROW 24      // shorts per hK0 key row (48 B)
#define KTS0 680     // shorts per VT0 dim row (21*32=672 keys + 8 pad)
#define H1ROW 20     // floats per h1 row (80 B, 16B-aligned, bank-friendly)
#define PROW 40      // shorts per P row
#define XROW 20      // floats per xls row

typedef __attribute__((ext_vector_type(8))) short bf16x8;
typedef __attribute__((ext_vector_type(4))) float f32x4;

// packed bf16 pair convert (RNE), 1 VALU op for 2 values
__device__ __forceinline__ unsigned cvtpk(float a, float b) {
    unsigned r;
    asm("v_cvt_pk_bf16_f32 %0, %1, %2" : "=v"(r) : "v"(a), "v"(b));
    return r;
}
__device__ __forceinline__ unsigned long long pk64(unsigned lo, unsigned hi) {
    return (unsigned long long)lo | ((unsigned long long)hi << 32);
}

// ======= prep: zero the forecast accumulator region (must precede all atomics) ===
__global__ __launch_bounds__(256) void prep_kernel(float* __restrict__ out)
{
    int t = blockIdx.x * 256 + threadIdx.x;   // 3072 float4 = 12288 floats
    if (t < BB * DD * NFF * NN / 4) {
        float4 z; z.x = z.y = z.z = z.w = 0.f;
        ((float4*)out)[t] = z;
    }
}

// ======= mega: both layers + tail scatter in ONE node (sync-free via halo
// recompute). Block = (bh, ri): owns L1 patches [a, a+4), a = ri*4; computes
// L0 for the halo [a, min(32,a+13)) itself; intra-block __syncthreads is the
// only synchronization. Tail contributions scattered by fire-and-forget
// atomics (round-9 verified). Numerics identical to round 9 (L0 recompute is
// deterministic; h1 kept fp32 like hA was).
// LDS 118016 B -> 1 block/CU; grid 256 = 1 block per CU.
__global__ __launch_bounds__(512) void mega_kernel(
    const float* __restrict__ tokens,
    const float* __restrict__ log_scales, const float* __restrict__ attn_norm,
    const float* __restrict__ up_w, const float* __restrict__ down_w,
    const float* __restrict__ ffn_norm,
    const float* __restrict__ mix_w, const float* __restrict__ mix_b,
    const float* __restrict__ fore_w, const float* __restrict__ fore_b,
    const float* __restrict__ x_orig, float* __restrict__ out)
{
    __shared__ short hK0[672 * KROW];      // 32256 B keys row-major (bf16)
    __shared__ short VT0[16 * KTS0];       // 21760 B keys dim-major (bf16)
    __shared__ float h1[13 * 32 * H1ROW];  // 33280 B layer-0 output rows (fp32)
    __shared__ short Pp[8][16 * PROW];     // 10240 B per-wave P+ buffers
    __shared__ short Pn[8][16 * PROW];     // 10240 B per-wave P- buffers
    __shared__ float xls[8][16 * XROW];    // 10240 B per-wave epilogue rows

    int blk = blockIdx.x;
    int bh  = blk >> 3;            // (b*8 + h)
    int hh  = bh & 7;
    int ri  = blk & 7;
    int a   = ri * 4;              // L1 patch range [a, a+4)
    int lo0 = a;
    int hi0 = min(32, a + 13);     // L0 halo [lo0, hi0)
    int P0  = hi0 - lo0;           // <= 13
    int klo = lo0 + 1;             // staged key patches [klo, khi)
    int khi = min(32, hi0 + 9);
    int KP0 = khi - klo;           // <= 21

    int tid  = threadIdx.x;
    int wid  = tid >> 6;           // 0..7
    int lane = tid & 63;
    int quad = lane >> 4, n16 = lane & 15;

    // ---- x passthrough: 64 float4 per block ----
    if (tid < 64) {
        const float4* x4 = (const float4*)x_orig;
        float4* o4 = (float4*)(out + BB * PREDL * NN);
        o4[blk * 64 + tid] = x4[blk * 64 + tid];
    }

    // ---- stage keys for L0: tokens fp32 -> bf16, row-major + dim-major ----
    {
        const float4* src = (const float4*)(tokens + ((size_t)bh * LL + klo * NN) * DD);
        int nf4 = KP0 * 128;       // KP0*32 rows x 4 float4
        for (int i = tid; i < nf4; i += 512) {
            int row = i >> 2, j = i & 3;
            float4 v = src[i];
            unsigned pk0 = cvtpk(v.x, v.y);
            unsigned pk1 = cvtpk(v.z, v.w);
            *(unsigned long long*)&hK0[row * KROW + j * 4] = pk64(pk0, pk1);
            int d0 = j * 4;
            VT0[(d0 + 0) * KTS0 + row] = (short)(pk0 & 0xffff);
            VT0[(d0 + 1) * KTS0 + row] = (short)(pk0 >> 16);
            VT0[(d0 + 2) * KTS0 + row] = (short)(pk1 & 0xffff);
            VT0[(d0 + 3) * KTS0 + row] = (short)(pk1 >> 16);
        }
    }

    float sc0 = fminf(fmaxf(__expf(log_scales[0]), 1.0f), 30.0f)
                * 0.25f * 1.4426950408889634f;
    float sc1 = fminf(fmaxf(__expf(log_scales[1]), 1.0f), 30.0f)
                * 0.25f * 1.4426950408889634f;

    short* myPp = Pp[wid];
    short* myPn = Pn[wid];
    float* myxls = xls[wid];

    __syncthreads();   // staging done

    // ================= LAYER 0: tasks = (patch, half), halo range =============
    {
        int ntask = P0 * 2;
        for (int t = wid; t < ntask; t += 8) {
            int pi = t >> 1, qh = t & 1;
            int p  = lo0 + pi;
            int nst = min(9, 31 - p);

            // Q A-frag + residual from global tokens
            bf16x8 Aq;
            #pragma unroll
            for (int j = 0; j < 8; ++j) Aq[j] = 0;
            if (quad < 2) {
                const float4* qp4 = (const float4*)(tokens +
                    ((size_t)bh * LL + p * NN + qh * 16 + n16) * DD + quad * 8);
                float4 A = qp4[0], B = qp4[1];
                union { bf16x8 v; unsigned u[4]; } uu;
                uu.u[0] = cvtpk(A.x, A.y); uu.u[1] = cvtpk(A.z, A.w);
                uu.u[2] = cvtpk(B.x, B.y); uu.u[3] = cvtpk(B.z, B.w);
                Aq = uu.v;
            }
            float rs[4];
            #pragma unroll
            for (int r = 0; r < 4; ++r)
                rs[r] = tokens[((size_t)bh * LL + p * NN + qh * 16 + quad * 4 + r) * DD + n16];

            f32x4 Op, On;
            Op[0] = Op[1] = Op[2] = Op[3] = 0.f;
            On[0] = On[1] = On[2] = On[3] = 0.f;
            float lpp = 0.f, lnn = 0.f;

            for (int c = 0; c < nst; ++c) {
                int kb = (p + 1 + c - klo) * 32;   // local key row base
                #pragma unroll
                for (int kt = 0; kt < 2; ++kt) {
                    bf16x8 Bk;
                    #pragma unroll
                    for (int j = 0; j < 8; ++j) Bk[j] = 0;
                    if (quad < 2)
                        Bk = *(const bf16x8*)&hK0[(kb + kt * 16 + n16) * KROW + quad * 8];
                    f32x4 z; z[0] = z[1] = z[2] = z[3] = 0.f;
                    f32x4 S = __builtin_amdgcn_mfma_f32_16x16x32_bf16(Bk, Aq, z, 0, 0, 0);
                    float ep[4], en[4];
                    #pragma unroll
                    for (int r = 0; r < 4; ++r) {
                        float tt = sc0 * S[r];
                        ep[r] = exp2f(tt);
                        en[r] = exp2f(-tt);
                        lpp += ep[r]; lnn += en[r];
                    }
                    *(unsigned long long*)&myPp[n16 * PROW + kt * 16 + quad * 4] =
                        pk64(cvtpk(ep[0], ep[1]), cvtpk(ep[2], ep[3]));
                    *(unsigned long long*)&myPn[n16 * PROW + kt * 16 + quad * 4] =
                        pk64(cvtpk(en[0], en[1]), cvtpk(en[2], en[3]));
                }
                bf16x8 Bv = *(const bf16x8*)&VT0[n16 * KTS0 + kb + quad * 8];
                bf16x8 Ap = *(const bf16x8*)&myPp[n16 * PROW + quad * 8];
                bf16x8 An = *(const bf16x8*)&myPn[n16 * PROW + quad * 8];
                Op = __builtin_amdgcn_mfma_f32_16x16x32_bf16(Ap, Bv, Op, 0, 0, 0);
                On = __builtin_amdgcn_mfma_f32_16x16x32_bf16(An, Bv, On, 0, 0, 0);
            }

            // lp/ln totals per query (sum over quads)
            lpp += __shfl_xor(lpp, 16); lpp += __shfl_xor(lpp, 32);
            lnn += __shfl_xor(lnn, 16); lnn += __shfl_xor(lnn, 32);
            float lpr[4], lnr[4];
            #pragma unroll
            for (int r = 0; r < 4; ++r) {
                lpr[r] = __shfl(lpp, quad * 4 + r);
                lnr[r] = __shfl(lnn, quad * 4 + r);
            }

            // residual + attn RMSNorm -> per-wave xls (16 rows)
            #pragma unroll
            for (int r = 0; r < 4; ++r) {
                float lp = lpr[r], ln = lnr[r];
                float rl = (lp > 0.f) ? (1.0f / lp) : 0.f;
                float rn = (ln > 0.f) ? (1.0f / ln) : 0.f;
                float v  = rs[r] + Op[r] * rl - On[r] * rn;
                float ss = v * v;
                ss += __shfl_xor(ss, 1); ss += __shfl_xor(ss, 2);
                ss += __shfl_xor(ss, 4); ss += __shfl_xor(ss, 8);
                float rr = rsqrtf(ss * (1.0f / 16.0f) + EPSF);
                myxls[(quad * 4 + r) * XROW + n16] = v * rr * attn_norm[0 * DD + n16];
            }
            // same-wave LDS ordering -> no barrier

            // conv-FFN + residual + RMSNorm: 64 lanes (16 q x 4 d-groups)
            {
                int q = n16;           // local query row 0..15
                int g = quad;

                const float* uw = up_w + (size_t)(0 * 2 * HH + 2 * hh) * 3;
                float w00 = uw[0], w01 = uw[1], w02 = uw[2];
                float w10 = uw[3], w11 = uw[4], w12 = uw[5];
                const float* dw = down_w + (size_t)(0 * HH + hh) * 2;
                float dc0 = dw[0], dc1 = dw[1];

                float xm2 = g ? myxls[q * XROW + 4 * g - 2] : 0.f;
                float xm1 = g ? myxls[q * XROW + 4 * g - 1] : 0.f;
                float4 xv = *(const float4*)&myxls[q * XROW + 4 * g];
                float xa[6] = {xm2, xm1, xv.x, xv.y, xv.z, xv.w};

                float v4[4], ss = 0.f;
                #pragma unroll
                for (int i = 0; i < 4; ++i) {
                    float u0 = w00 * xa[i] + w01 * xa[i + 1] + w02 * xa[i + 2];
                    float u1 = w10 * xa[i] + w11 * xa[i + 1] + w12 * xa[i + 2];
                    float g0 = 0.5f * u0 * (1.0f + erff(u0 * 0.7071067811865475f));
                    float g1 = 0.5f * u1 * (1.0f + erff(u1 * 0.7071067811865475f));
                    float vv = xa[i + 2] + dc0 * g0 + dc1 * g1;
                    v4[i] = vv; ss += vv * vv;
                }
                ss += __shfl_xor(ss, 16); ss += __shfl_xor(ss, 32);
                float r2 = rsqrtf(ss * (1.0f / 16.0f) + EPSF);

                const float4 fn = *(const float4*)&ffn_norm[0 * DD + 4 * g];
                float4 o;
                o.x = v4[0] * r2 * fn.x;
                o.y = v4[1] * r2 * fn.y;
                o.z = v4[2] * r2 * fn.z;
                o.w = v4[3] * r2 * fn.w;
                *(float4*)&h1[(pi * 32 + qh * 16 + q) * H1ROW + 4 * g] = o;
            }
        }
    }

    __syncthreads();   // h1 complete for [lo0, hi0)

    // ================= LAYER 1: 8 tasks, one per wave (patches [a, a+4)) =====
    {
        int pi1 = wid >> 1, qh = wid & 1;
        int p   = a + pi1;
        int nst = min(9, 31 - p);

        // Q A-frag + residual from h1 (fp32 LDS)
        bf16x8 Aq;
        #pragma unroll
        for (int j = 0; j < 8; ++j) Aq[j] = 0;
        if (quad < 2) {
            const float* qp = &h1[(pi1 * 32 + qh * 16 + n16) * H1ROW + quad * 8];
            float4 A = *(const float4*)qp;
            float4 B = *(const float4*)(qp + 4);
            union { bf16x8 v; unsigned u[4]; } uu;
            uu.u[0] = cvtpk(A.x, A.y); uu.u[1] = cvtpk(A.z, A.w);
            uu.u[2] = cvtpk(B.x, B.y); uu.u[3] = cvtpk(B.z, B.w);
            Aq = uu.v;
        }
        float rs[4];
        #pragma unroll
        for (int r = 0; r < 4; ++r)
            rs[r] = h1[(pi1 * 32 + qh * 16 + quad * 4 + r) * H1ROW + n16];

        f32x4 Op, On;
        Op[0] = Op[1] = Op[2] = Op[3] = 0.f;
        On[0] = On[1] = On[2] = On[3] = 0.f;
        float lpp = 0.f, lnn = 0.f;

        for (int c = 0; c < nst; ++c) {
            int kb = (pi1 + 1 + c) * 32;   // h1-local key row base
            #pragma unroll
            for (int kt = 0; kt < 2; ++kt) {
                bf16x8 Bk;
                #pragma unroll
                for (int j = 0; j < 8; ++j) Bk[j] = 0;
                if (quad < 2) {
                    const float* kp_ = &h1[(kb + kt * 16 + n16) * H1ROW + quad * 8];
                    float4 A = *(const float4*)kp_;
                    float4 B = *(const float4*)(kp_ + 4);
                    union { bf16x8 v; unsigned u[4]; } uu;
                    uu.u[0] = cvtpk(A.x, A.y); uu.u[1] = cvtpk(A.z, A.w);
                    uu.u[2] = cvtpk(B.x, B.y); uu.u[3] = cvtpk(B.z, B.w);
                    Bk = uu.v;
                }
                f32x4 z; z[0] = z[1] = z[2] = z[3] = 0.f;
                f32x4 S = __builtin_amdgcn_mfma_f32_16x16x32_bf16(Bk, Aq, z, 0, 0, 0);
                float ep[4], en[4];
                #pragma unroll
                for (int r = 0; r < 4; ++r) {
                    float tt = sc1 * S[r];
                    ep[r] = exp2f(tt);
                    en[r] = exp2f(-tt);
                    lpp += ep[r]; lnn += en[r];
                }
                *(unsigned long long*)&myPp[n16 * PROW + kt * 16 + quad * 4] =
                    pk64(cvtpk(ep[0], ep[1]), cvtpk(ep[2], ep[3]));
                *(unsigned long long*)&myPn[n16 * PROW + kt * 16 + quad * 4] =
                    pk64(cvtpk(en[0], en[1]), cvtpk(en[2], en[3]));
            }
            // V B-frag from h1 dim n16, keys kb+quad*8..+7
            bf16x8 Bv;
            {
                float v0 = h1[(kb + quad * 8 + 0) * H1ROW + n16];
                float v1 = h1[(kb + quad * 8 + 1) * H1ROW + n16];
                float v2 = h1[(kb + quad * 8 + 2) * H1ROW + n16];
                float v3 = h1[(kb + quad * 8 + 3) * H1ROW + n16];
                float v4_ = h1[(kb + quad * 8 + 4) * H1ROW + n16];
                float v5 = h1[(kb + quad * 8 + 5) * H1ROW + n16];
                float v6 = h1[(kb + quad * 8 + 6) * H1ROW + n16];
                float v7 = h1[(kb + quad * 8 + 7) * H1ROW + n16];
                union { bf16x8 v; unsigned u[4]; } uu;
                uu.u[0] = cvtpk(v0, v1); uu.u[1] = cvtpk(v2, v3);
                uu.u[2] = cvtpk(v4_, v5); uu.u[3] = cvtpk(v6, v7);
                Bv = uu.v;
            }
            bf16x8 Ap = *(const bf16x8*)&myPp[n16 * PROW + quad * 8];
            bf16x8 An = *(const bf16x8*)&myPn[n16 * PROW + quad * 8];
            Op = __builtin_amdgcn_mfma_f32_16x16x32_bf16(Ap, Bv, Op, 0, 0, 0);
            On = __builtin_amdgcn_mfma_f32_16x16x32_bf16(An, Bv, On, 0, 0, 0);
        }

        lpp += __shfl_xor(lpp, 16); lpp += __shfl_xor(lpp, 32);
        lnn += __shfl_xor(lnn, 16); lnn += __shfl_xor(lnn, 32);
        float lpr[4], lnr[4];
        #pragma unroll
        for (int r = 0; r < 4; ++r) {
            lpr[r] = __shfl(lpp, quad * 4 + r);
            lnr[r] = __shfl(lnn, quad * 4 + r);
        }

        #pragma unroll
        for (int r = 0; r < 4; ++r) {
            float lp = lpr[r], ln = lnr[r];
            float rl = (lp > 0.f) ? (1.0f / lp) : 0.f;
            float rn = (ln > 0.f) ? (1.0f / ln) : 0.f;
            float v  = rs[r] + Op[r] * rl - On[r] * rn;
            float ss = v * v;
            ss += __shfl_xor(ss, 1); ss += __shfl_xor(ss, 2);
            ss += __shfl_xor(ss, 4); ss += __shfl_xor(ss, 8);
            float rr = rsqrtf(ss * (1.0f / 16.0f) + EPSF);
            myxls[(quad * 4 + r) * XROW + n16] = v * rr * attn_norm[1 * DD + n16];
        }

        // conv-FFN + residual + RMSNorm + atomic tail scatter
        {
            int q = qh * 16 + n16;     // channel n within patch p
            int g = quad;

            const float* uw = up_w + (size_t)(1 * 2 * HH + 2 * hh) * 3;
            float w00 = uw[0], w01 = uw[1], w02 = uw[2];
            float w10 = uw[3], w11 = uw[4], w12 = uw[5];
            const float* dw = down_w + (size_t)(1 * HH + hh) * 2;
            float dc0 = dw[0], dc1 = dw[1];

            float xm2 = g ? myxls[n16 * XROW + 4 * g - 2] : 0.f;
            float xm1 = g ? myxls[n16 * XROW + 4 * g - 1] : 0.f;
            float4 xv = *(const float4*)&myxls[n16 * XROW + 4 * g];
            float xa[6] = {xm2, xm1, xv.x, xv.y, xv.z, xv.w};

            float v4[4], ss = 0.f;
            #pragma unroll
            for (int i = 0; i < 4; ++i) {
                float u0 = w00 * xa[i] + w01 * xa[i + 1] + w02 * xa[i + 2];
                float u1 = w10 * xa[i] + w11 * xa[i + 1] + w12 * xa[i + 2];
                float g0 = 0.5f * u0 * (1.0f + erff(u0 * 0.7071067811865475f));
                float g1 = 0.5f * u1 * (1.0f + erff(u1 * 0.7071067811865475f));
                float vv = xa[i + 2] + dc0 * g0 + dc1 * g1;
                v4[i] = vv; ss += vv * vv;
            }
            ss += __shfl_xor(ss, 16); ss += __shfl_xor(ss, 32);
            float r2 = rsqrtf(ss * (1.0f / 16.0f) + EPSF);

            const float4 fn = *(const float4*)&ffn_norm[1 * DD + 4 * g];
            float vals[4];
            vals[0] = v4[0] * r2 * fn.x;
            vals[1] = v4[1] * r2 * fn.y;
            vals[2] = v4[2] * r2 * fn.z;
            vals[3] = v4[3] * r2 * fn.w;

            // out[b, d=4g+i, fi, n=q] += mw[h]*fw[fi,p]*vals[i] (+const once)
            int b2 = bh >> 3;
            float mwh = mix_w[hh];
            bool isc = (hh == 0) && (p == 0);
            float mbv = mix_b[0];
            #pragma unroll
            for (int fi = 0; fi < NFF; ++fi) {
                float cst = 0.f;
                if (isc) {
                    float s = 0.f;
                    for (int pp = 0; pp < PP; ++pp) s += fore_w[fi * PP + pp];
                    cst = fore_b[fi] + mbv * s;
                }
                float cc = mwh * fore_w[fi * PP + p];
                #pragma unroll
                for (int i = 0; i < 4; ++i)
                    atomicAdd(&out[((size_t)(b2 * DD + 4 * g + i) * NFF + fi) * NN + q],
                              cc * vals[i] + cst);
            }
        }
    }
}

// ---------------- host-side input identification by element count ----------------
static int find_by_size(const int* s, int n, int want, int occurrence) {
    int seen = 0;
    for (int i = 0; i < n; ++i)
        if (s[i] == want) { if (seen == occurrence) return i; ++seen; }
    return -1;
}

extern "C" void kernel_launch(void* const* d_in, const int* in_sizes, int n_in,
                              void* d_out, int out_size, void* d_ws, size_t ws_size,
                              hipStream_t stream) {
    int it  = find_by_size(in_sizes, n_in, 524288, 0);
    int ix  = find_by_size(in_sizes, n_in, 65536, 0);
    int ils = find_by_size(in_sizes, n_in, 2, 0);
    int ian = find_by_size(in_sizes, n_in, 32, 0);   // attn_norm_w (1st 32)
    int icu = find_by_size(in_sizes, n_in, 96, 0);
    int icd = find_by_size(in_sizes, n_in, 32, 1);   // conv_down_w (2nd 32)
    int ifn = find_by_size(in_sizes, n_in, 32, 2);   // ffn_norm_w  (3rd 32)
    int imw = find_by_size(in_sizes, n_in, 8, 0);
    int imb = find_by_size(in_sizes, n_in, 1, 0);
    int ifw = find_by_size(in_sizes, n_in, 192, 0);
    int ifb = find_by_size(in_sizes, n_in, 6, 0);
    if (it < 0 || ix < 0 || ils < 0 || ian < 0 || icu < 0 || icd < 0 ||
        ifn < 0 || imw < 0 || imb < 0 || ifw < 0 || ifb < 0) {
        it = 0; ix = 1; ils = 2; ian = 3; icu = 4; icd = 5; ifn = 6;
        imw = 7; imb = 8; ifw = 9; ifb = 10;
    }

    const float* tokens     = (const float*)d_in[it];
    const float* x_orig     = (const float*)d_in[ix];
    const float* log_scales = (const float*)d_in[ils];
    const float* attn_norm  = (const float*)d_in[ian];
    const float* up_w       = (const float*)d_in[icu];
    const float* down_w     = (const float*)d_in[icd];
    const float* ffn_norm   = (const float*)d_in[ifn];
    const float* mix_w      = (const float*)d_in[imw];
    const float* mix_b      = (const float*)d_in[imb];
    const float* fore_w     = (const float*)d_in[ifw];
    const float* fore_b     = (const float*)d_in[ifb];
    float* out = (float*)d_out;

    prep_kernel<<<12, 256, 0, stream>>>(out);
    mega_kernel<<<256, 512, 0, stream>>>(tokens, log_scales, attn_norm,
                                         up_w, down_w, ffn_norm,
                                         mix_w, mix_b, fore_w, fore_b,
                                         x_orig, out);
}

// Round 11
// 108.394 us; speedup vs baseline: 1.1068x; 1.1068x over previous
//
#include <hip/hip_runtime.h>
#include <hip/hip_bf16.h>
#include <math.h>

#define BB 4
#define HH 8
#define PP 32
#define NN 32
#define DD 16
#define LL 1024      // PP*NN
#define WINW 10
#define NFF 6
#define PREDL 96
#define SEQL 512
#define EPSF 1.1920928955078125e-07f
#define KROW 24      // shorts per staged key row (48 B, 16B-aligned)
#define KTS 296      // shorts per VT row (288 keys + 8 pad; 592 B, 16B-aligned)
#define PROW 40      // shorts per P row (80 B, 16B-aligned)
#define XROW 20      // floats per xls row (80 B, 16B-aligned)

typedef __attribute__((ext_vector_type(8))) short bf16x8;
typedef __attribute__((ext_vector_type(4))) float f32x4;

// packed bf16 pair convert (RNE), 1 VALU op for 2 values
__device__ __forceinline__ unsigned cvtpk(float a, float b) {
    unsigned r;
    asm("v_cvt_pk_bf16_f32 %0, %1, %2" : "=v"(r) : "v"(a), "v"(b));
    return r;
}
__device__ __forceinline__ unsigned long long pk64(unsigned lo, unsigned hi) {
    return (unsigned long long)lo | ((unsigned long long)hi << 32);
}

// ======= one layer: signed banded attention + RMSNorm + convFFN + RMSNorm ===
// Round-9 verified math (swapped QK^T, cvt_pk packing, 110.9 us, passed).
// MODE 0: write hout rows (layer 0).
// MODE 1: no hout write; scatter tail contributions into out via
//         fire-and-forget global atomics (tail is linear in hB):
//         out[b,d,fi,n] += mw[h]*fw[fi,p0]*val[n,d]  (+const on h==0,p0==0)
template <int MODE>
__device__ __forceinline__ void layer_body(
    const float* __restrict__ hin, float* __restrict__ hout,
    const float* __restrict__ log_scales, const float* __restrict__ attn_norm,
    const float* __restrict__ up_w, const float* __restrict__ down_w,
    const float* __restrict__ ffn_norm, int layer, int blk, int tid,
    short* hK, short* VT, short (*Pp)[16 * PROW], short (*Pn)[16 * PROW],
    float* xls, float (*comb)[64][8], float (*combl)[2][16],
    const float* __restrict__ mix_w, const float* __restrict__ mix_b,
    const float* __restrict__ fore_w, const float* __restrict__ fore_b,
    float* __restrict__ out)
{
    int bh  = blk >> 5;            // (b*8+h)
    int hh  = bh & 7;
    int p0  = blk & 31;
    int nstage = min(9, (PP - 1) - p0);

    int wid  = tid >> 6;           // wave id
    int qh   = wid >> 1;           // query half (0/1)
    int ch   = wid & 1;            // chunk half (0/1)
    int lane = tid & 63;
    int quad = lane >> 4, n16 = lane & 15;

    // ---- stage keys: fp32 -> bf16 (cvt_pk), row-major + transposed ----
    {
        const float4* src = (const float4*)(hin + ((size_t)bh * LL + (p0 + 1) * NN) * DD);
        int nf4 = nstage * 128;
        #pragma unroll
        for (int k = 0; k < 5; ++k) {
            int i = tid + k * 256;
            if (i < nf4) {
                int row = i >> 2, j = i & 3;
                float4 v = src[i];
                unsigned pk0 = cvtpk(v.x, v.y);
                unsigned pk1 = cvtpk(v.z, v.w);
                *(unsigned long long*)&hK[row * KROW + j * 4] = pk64(pk0, pk1);
                int d0 = j * 4;
                VT[(d0 + 0) * KTS + row] = (short)(pk0 & 0xffff);
                VT[(d0 + 1) * KTS + row] = (short)(pk0 >> 16);
                VT[(d0 + 2) * KTS + row] = (short)(pk1 & 0xffff);
                VT[(d0 + 3) * KTS + row] = (short)(pk1 >> 16);
            }
        }
    }

    // ---- preload Q B-frag and residual (global; overlaps staging) ----
    bf16x8 Aq;
    #pragma unroll
    for (int j = 0; j < 8; ++j) Aq[j] = 0;
    if (quad < 2) {
        const float4* qp4 = (const float4*)(hin +
            ((size_t)bh * LL + p0 * NN + qh * 16 + n16) * DD + quad * 8);
        float4 a = qp4[0], b = qp4[1];
        union { bf16x8 v; unsigned u[4]; } uu;
        uu.u[0] = cvtpk(a.x, a.y);
        uu.u[1] = cvtpk(a.z, a.w);
        uu.u[2] = cvtpk(b.x, b.y);
        uu.u[3] = cvtpk(b.z, b.w);
        Aq = uu.v;
    }
    float rs[4] = {0.f, 0.f, 0.f, 0.f};
    if (ch == 0) {
        #pragma unroll
        for (int r = 0; r < 4; ++r)
            rs[r] = hin[((size_t)bh * LL + p0 * NN + qh * 16 + quad * 4 + r) * DD + n16];
    }

    float sc  = fminf(fmaxf(__expf(log_scales[layer]), 1.0f), 30.0f) * 0.25f;
    float sc2 = sc * 1.4426950408889634f;   // fold log2(e): exp(x) == exp2(sc2*s)

    __syncthreads();   // staging done

    // ---- chunk loop: ch==0 -> chunks [0,4), ch==1 -> chunks [4,nstage) ----
    f32x4 Op, On;
    Op[0] = Op[1] = Op[2] = Op[3] = 0.f;
    On[0] = On[1] = On[2] = On[3] = 0.f;
    float lpp = 0.f, lnn = 0.f;    // per-lane partial for query n16
    short* myPp = Pp[wid];
    short* myPn = Pn[wid];

    int c0 = ch ? 4 : 0;
    int c1 = ch ? nstage : min(4, nstage);

    for (int c = c0; c < c1; ++c) {
        int kb = c * 32;
        #pragma unroll
        for (int kt = 0; kt < 2; ++kt) {
            bf16x8 Bk;   // K fragment (A operand after swap)
            #pragma unroll
            for (int j = 0; j < 8; ++j) Bk[j] = 0;
            if (quad < 2)
                Bk = *(const bf16x8*)&hK[(kb + kt * 16 + n16) * KROW + quad * 8];
            f32x4 z; z[0] = z[1] = z[2] = z[3] = 0.f;
            // SWAPPED: S'[key kt*16+quad*4+r][query n16]
            f32x4 S = __builtin_amdgcn_mfma_f32_16x16x32_bf16(Bk, Aq, z, 0, 0, 0);
            float ep[4], en[4];
            #pragma unroll
            for (int r = 0; r < 4; ++r) {
                float t = sc2 * S[r];
                ep[r] = exp2f(t);
                en[r] = exp2f(-t);
                lpp += ep[r]; lnn += en[r];
            }
            // one b64 write per P-type: P[query n16][keys kt*16+quad*4 .. +3]
            *(unsigned long long*)&myPp[n16 * PROW + kt * 16 + quad * 4] =
                pk64(cvtpk(ep[0], ep[1]), cvtpk(ep[2], ep[3]));
            *(unsigned long long*)&myPn[n16 * PROW + kt * 16 + quad * 4] =
                pk64(cvtpk(en[0], en[1]), cvtpk(en[2], en[3]));
        }
        // PV: contiguous b128 frags (same-wave LDS ordering via lgkmcnt)
        bf16x8 Bv = *(const bf16x8*)&VT[n16 * KTS + kb + quad * 8];
        bf16x8 Ap = *(const bf16x8*)&myPp[n16 * PROW + quad * 8];
        bf16x8 An = *(const bf16x8*)&myPn[n16 * PROW + quad * 8];
        Op = __builtin_amdgcn_mfma_f32_16x16x32_bf16(Ap, Bv, Op, 0, 0, 0);
        On = __builtin_amdgcn_mfma_f32_16x16x32_bf16(An, Bv, On, 0, 0, 0);
    }

    // ---- reduce lp/ln over quads (each lane then has full sum for query n16) ----
    lpp += __shfl_xor(lpp, 16); lpp += __shfl_xor(lpp, 32);
    lnn += __shfl_xor(lnn, 16); lnn += __shfl_xor(lnn, 32);

    // ---- merge ch==1 partials into ch==0 waves ----
    if (ch == 1) {
        *(f32x4*)&comb[qh][lane][0] = Op;
        *(f32x4*)&comb[qh][lane][4] = On;
        if (lane < 16) {
            combl[qh][0][lane] = lpp;
            combl[qh][1][lane] = lnn;
        }
    }
    __syncthreads();
    if (ch == 1) return;   // no barriers past this point

    {
        f32x4 o2 = *(const f32x4*)&comb[qh][lane][0];
        f32x4 n2 = *(const f32x4*)&comb[qh][lane][4];
        #pragma unroll
        for (int r = 0; r < 4; ++r) { Op[r] += o2[r]; On[r] += n2[r]; }
        lpp += combl[qh][0][n16];
        lnn += combl[qh][1][n16];
    }

    // redistribute lp/ln to the O-fragment's row indexing (query quad*4+r)
    float lpr[4], lnr[4];
    #pragma unroll
    for (int r = 0; r < 4; ++r) {
        lpr[r] = __shfl(lpp, quad * 4 + r);
        lnr[r] = __shfl(lnn, quad * 4 + r);
    }

    // ---- residual + attn RMSNorm (C-layout), stash rows to xls ----
    #pragma unroll
    for (int r = 0; r < 4; ++r) {
        float lp = lpr[r], ln = lnr[r];
        float rl = (lp > 0.f) ? (1.0f / lp) : 0.f;
        float rn = (ln > 0.f) ? (1.0f / ln) : 0.f;
        float v  = rs[r] + Op[r] * rl - On[r] * rn;
        float ss = v * v;
        ss += __shfl_xor(ss, 1); ss += __shfl_xor(ss, 2);
        ss += __shfl_xor(ss, 4); ss += __shfl_xor(ss, 8);
        float rr = rsqrtf(ss * (1.0f / 16.0f) + EPSF);
        xls[(qh * 16 + quad * 4 + r) * XROW + n16] = v * rr * attn_norm[layer * DD + n16];
    }
    // this wave wrote all 16 of its xls rows -> same-wave LDS ordering, no barrier

    // ---- conv-FFN + residual + RMSNorm: all 64 lanes (16 q x 4 i-groups) ----
    {
        int q = qh * 16 + n16;       // channel n / row within block
        int g = quad;                // d-group: d = 4g..4g+3

        const float* uw = up_w + (size_t)(layer * 2 * HH + 2 * hh) * 3;
        float w00 = uw[0], w01 = uw[1], w02 = uw[2];
        float w10 = uw[3], w11 = uw[4], w12 = uw[5];
        const float* dw = down_w + (size_t)(layer * HH + hh) * 2;
        float dc0 = dw[0], dc1 = dw[1];

        float xm2 = g ? xls[q * XROW + 4 * g - 2] : 0.f;
        float xm1 = g ? xls[q * XROW + 4 * g - 1] : 0.f;
        float4 xv = *(const float4*)&xls[q * XROW + 4 * g];
        float xa[6] = {xm2, xm1, xv.x, xv.y, xv.z, xv.w};

        float v4[4], ss = 0.f;
        #pragma unroll
        for (int i = 0; i < 4; ++i) {
            float u0 = w00 * xa[i] + w01 * xa[i + 1] + w02 * xa[i + 2];
            float u1 = w10 * xa[i] + w11 * xa[i + 1] + w12 * xa[i + 2];
            float g0 = 0.5f * u0 * (1.0f + erff(u0 * 0.7071067811865475f));
            float g1 = 0.5f * u1 * (1.0f + erff(u1 * 0.7071067811865475f));
            float vv = xa[i] * 0.f + xa[i + 2] + dc0 * g0 + dc1 * g1;
            v4[i] = vv; ss += vv * vv;
        }
        ss += __shfl_xor(ss, 16); ss += __shfl_xor(ss, 32);
        float r2 = rsqrtf(ss * (1.0f / 16.0f) + EPSF);

        const float4 fn = *(const float4*)&ffn_norm[layer * DD + 4 * g];
        float vals[4];
        vals[0] = v4[0] * r2 * fn.x;
        vals[1] = v4[1] * r2 * fn.y;
        vals[2] = v4[2] * r2 * fn.z;
        vals[3] = v4[3] * r2 * fn.w;

        if (MODE == 0) {
            float* op = hout + ((size_t)bh * LL + p0 * NN + q) * DD + 4 * g;
            *(float4*)op = *(float4*)vals;
        } else {
            // tail scatter: out[b, d=4g+i, fi, n=q] += mw[h]*fw[fi,p0]*vals[i]
            // (+ fb[fi] + mb*sum_p fw[fi,p], folded into the h==0,p0==0 blocks)
            int b2 = bh >> 3;
            float mwh = mix_w[hh];
            bool isc = (hh == 0) && (p0 == 0);
            float mbv = mix_b[0];
            #pragma unroll
            for (int fi = 0; fi < NFF; ++fi) {
                float cst = 0.f;
                if (isc) {
                    float s = 0.f;
                    for (int p = 0; p < PP; ++p) s += fore_w[fi * PP + p];
                    cst = fore_b[fi] + mbv * s;
                }
                float c = mwh * fore_w[fi * PP + p0];
                #pragma unroll
                for (int i = 0; i < 4; ++i)
                    atomicAdd(&out[((size_t)(b2 * DD + 4 * g + i) * NFF + fi) * NN + q],
                              c * vals[i] + cst);
            }
        }
    }
}

// ======= dispatch 1: layer 0 + x-passthrough + out-tail zeroing ==============
__global__ __launch_bounds__(256) void layer0_kernel(
    const float* __restrict__ tokens, float* __restrict__ hA,
    const float* __restrict__ log_scales, const float* __restrict__ attn_norm,
    const float* __restrict__ up_w, const float* __restrict__ down_w,
    const float* __restrict__ ffn_norm,
    const float* __restrict__ x_orig, float* __restrict__ out)
{
    __shared__ short hK[9 * 32 * KROW];
    __shared__ short VT[16 * KTS];
    __shared__ short Pp[4][16 * PROW];
    __shared__ short Pn[4][16 * PROW];
    __shared__ float xls[32 * XROW];
    __shared__ float comb[2][64][8];
    __shared__ float combl[2][2][16];

    int blk = blockIdx.x;
    int tid = threadIdx.x;

    // zero the forecast region (12288 floats = 3072 float4; 3 per block)
    if (tid < 3) {
        float4 z; z.x = z.y = z.z = z.w = 0.f;
        ((float4*)out)[blk * 3 + tid] = z;
    }
    // x passthrough: 16 float4 per block
    if (tid < 16) {
        const float4* x4 = (const float4*)x_orig;
        float4* o4 = (float4*)(out + BB * PREDL * NN);
        o4[blk * 16 + tid] = x4[blk * 16 + tid];
    }

    layer_body<0>(tokens, hA, log_scales, attn_norm, up_w, down_w, ffn_norm, 0,
                  blk, tid, hK, VT, Pp, Pn, xls, comb, combl,
                  nullptr, nullptr, nullptr, nullptr, nullptr);
}

// ======= dispatch 2: layer 1 + atomic tail scatter (no hB, no 3rd node) =====
__global__ __launch_bounds__(256) void layer1_kernel(
    const float* __restrict__ hA,
    const float* __restrict__ log_scales, const float* __restrict__ attn_norm,
    const float* __restrict__ up_w, const float* __restrict__ down_w,
    const float* __restrict__ ffn_norm,
    const float* __restrict__ mix_w, const float* __restrict__ mix_b,
    const float* __restrict__ fore_w, const float* __restrict__ fore_b,
    float* __restrict__ out)
{
    __shared__ short hK[9 * 32 * KROW];
    __shared__ short VT[16 * KTS];
    __shared__ short Pp[4][16 * PROW];
    __shared__ short Pn[4][16 * PROW];
    __shared__ float xls[32 * XROW];
    __shared__ float comb[2][64][8];
    __shared__ float combl[2][2][16];

    int blk = blockIdx.x;
    int tid = threadIdx.x;

    layer_body<1>(hA, nullptr, log_scales, attn_norm, up_w, down_w, ffn_norm, 1,
                  blk, tid, hK, VT, Pp, Pn, xls, comb, combl,
                  mix_w, mix_b, fore_w, fore_b, out);
}

// ---------------- host-side input identification by element count ----------------
static int find_by_size(const int* s, int n, int want, int occurrence) {
    int seen = 0;
    for (int i = 0; i < n; ++i)
        if (s[i] == want) { if (seen == occurrence) return i; ++seen; }
    return -1;
}

extern "C" void kernel_launch(void* const* d_in, const int* in_sizes, int n_in,
                              void* d_out, int out_size, void* d_ws, size_t ws_size,
                              hipStream_t stream) {
    int it  = find_by_size(in_sizes, n_in, 524288, 0);
    int ix  = find_by_size(in_sizes, n_in, 65536, 0);
    int ils = find_by_size(in_sizes, n_in, 2, 0);
    int ian = find_by_size(in_sizes, n_in, 32, 0);   // attn_norm_w (1st 32)
    int icu = find_by_size(in_sizes, n_in, 96, 0);
    int icd = find_by_size(in_sizes, n_in, 32, 1);   // conv_down_w (2nd 32)
    int ifn = find_by_size(in_sizes, n_in, 32, 2);   // ffn_norm_w  (3rd 32)
    int imw = find_by_size(in_sizes, n_in, 8, 0);
    int imb = find_by_size(in_sizes, n_in, 1, 0);
    int ifw = find_by_size(in_sizes, n_in, 192, 0);
    int ifb = find_by_size(in_sizes, n_in, 6, 0);
    if (it < 0 || ix < 0 || ils < 0 || ian < 0 || icu < 0 || icd < 0 ||
        ifn < 0 || imw < 0 || imb < 0 || ifw < 0 || ifb < 0) {
        it = 0; ix = 1; ils = 2; ian = 3; icu = 4; icd = 5; ifn = 6;
        imw = 7; imb = 8; ifw = 9; ifb = 10;
    }

    const float* tokens     = (const float*)d_in[it];
    const float* x_orig     = (const float*)d_in[ix];
    const float* log_scales = (const float*)d_in[ils];
    const float* attn_norm  = (const float*)d_in[ian];
    const float* up_w       = (const float*)d_in[icu];
    const float* down_w     = (const float*)d_in[icd];
    const float* ffn_norm   = (const float*)d_in[ifn];
    const float* mix_w      = (const float*)d_in[imw];
    const float* mix_b      = (const float*)d_in[imb];
    const float* fore_w     = (const float*)d_in[ifw];
    const float* fore_b     = (const float*)d_in[ifb];
    float* out = (float*)d_out;

    float* hA = (float*)d_ws;        // [0, 2 MB)

    layer0_kernel<<<1024, 256, 0, stream>>>(tokens, hA, log_scales, attn_norm,
                                            up_w, down_w, ffn_norm, x_orig, out);
    layer1_kernel<<<1024, 256, 0, stream>>>(hA, log_scales, attn_norm,
                                            up_w, down_w, ffn_norm,
                                            mix_w, mix_b, fore_w, fore_b, out);
}